// Round 3
// baseline (137.017 us; speedup 1.0000x reference)
//
#include <hip/hip_runtime.h>
#include <hip/hip_fp16.h>

// B=4, Cin=64, Cout=128, H=W=128, 3x3, stride=1, pad=1, dil=1
#define HW    16384
#define NB    4
#define CIN   64
#define COUT  128

typedef short  short8  __attribute__((ext_vector_type(8)));
typedef _Float16 half8 __attribute__((ext_vector_type(8)));
typedef float  floatx4 __attribute__((ext_vector_type(4)));

__device__ __forceinline__ unsigned packh2(float a, float b) {
  __half2 h = __floats2half2_rn(a, b);
  return *(unsigned*)&h;
}
__device__ __forceinline__ short f2h(float f) {
  __half h = __float2half(f);
  return *(short*)&h;
}

// ---- packed-f16 bilinear helpers: broadcast one half of w via op_sel ----
__device__ __forceinline__ unsigned pk_mul_blo(unsigned a, unsigned w) {
  unsigned d;
  asm("v_pk_mul_f16 %0, %1, %2 op_sel:[0,0] op_sel_hi:[1,0]"
      : "=v"(d) : "v"(a), "v"(w));
  return d;
}
__device__ __forceinline__ unsigned pk_fma_blo(unsigned a, unsigned w, unsigned c) {
  unsigned d;
  asm("v_pk_fma_f16 %0, %1, %2, %3 op_sel:[0,0,0] op_sel_hi:[1,0,1]"
      : "=v"(d) : "v"(a), "v"(w), "v"(c));
  return d;
}
__device__ __forceinline__ unsigned pk_fma_bhi(unsigned a, unsigned w, unsigned c) {
  unsigned d;
  asm("v_pk_fma_f16 %0, %1, %2, %3 op_sel:[0,1,0] op_sel_hi:[1,1,1]"
      : "=v"(d) : "v"(a), "v"(w), "v"(c));
  return d;
}

// ---------------------------------------------------------------------------
// k_tr: CHW fp32 -> HWC f16 for input_feat ONLY (xd) + fused weight prep.
// (inter is no longer transposed: k_dcn reads its halo straight from fp32.)
// ---------------------------------------------------------------------------
__global__ __launch_bounds__(256) void k_tr(const float* __restrict__ x,
                                            const float* __restrict__ weight,
                                            const float* __restrict__ w_om,
                                            short* __restrict__ xd,
                                            short* __restrict__ wtbF,
                                            short* __restrict__ wtbomF) {
  __shared__ unsigned sT[64][37];                 // 64 px x 32 ch-pairs (+pad)
  const int blk = blockIdx.x;
  const int b = blk >> 8, hw0 = (blk & 255) * 64;
  const int tid = threadIdx.x;
  const int px = tid & 63, cg = tid >> 6;
  const float* s0 = x + (size_t)b * CIN * HW + hw0 + px;
#pragma unroll
  for (int step = 0; step < 8; ++step) {
    int cp = step * 4 + cg;                       // ch-pair 0..31
    int c = cp * 2;
    sT[px][cp] = packh2(s0[c * HW], s0[(c + 1) * HW]);
  }
  // fused weight prep while LDS settles
  {
    int i = blk * 256 + tid;
    if (i < 73728) {
      int i8 = i & 7, l = (i >> 3) & 15, q = (i >> 7) & 3;
      int t = (i >> 9) & 1, wv = (i >> 10) & 3, s = i >> 12;
      int o = wv * 32 + t * 16 + l;
      int k = s * 32 + q * 8 + i8;
      int c = k & 63, tap = k >> 6;
      wtbF[i] = f2h(weight[o * 576 + c * 9 + tap]);
    }
    if (i < 36864) {
      int i8 = i & 7, l = (i >> 3) & 15, q = (i >> 7) & 3;
      int t = (i >> 9) & 1, s = i >> 10;
      int o = t * 16 + l;
      int k = s * 32 + q * 8 + i8;
      int c = k & 127, tap = k >> 7;
      wtbomF[i] = (o < 27) ? f2h(w_om[o * 1152 + c * 9 + tap]) : (short)0;
    }
  }
  __syncthreads();
  const int od = tid & 7, p0 = tid >> 3;
#pragma unroll
  for (int it = 0; it < 2; ++it) {
    int p = p0 + it * 32;
    uint4 a;
    a.x = sT[p][od * 4 + 0]; a.y = sT[p][od * 4 + 1];
    a.z = sT[p][od * 4 + 2]; a.w = sT[p][od * 4 + 3];
    size_t base = ((size_t)b * HW + hw0 + p) * 64 + od * 8;
    *(uint4*)(xd + base) = a;
  }
}

// ---------------------------------------------------------------------------
// k_dcn: FUSED offset/mask conv + modulated deformable conv. 32-px tile.
// LDS = 26112 B -> 6 blocks/CU:
//  sH    @0      halo 3x34x128ch f16             26112 B (live A->B)
//  sPart @0      om partials [kh2][27r][32c] f32  6912 B (live postB->C)
//  sPar  @20480  packed bilinear params           3456 B (live C->D2, outside sV)
//  sV    @0      V panel [tapLoc*32+px][64] XOR   <=20480 B (5-tap / 4-tap halves)
// Phase A : halo ch 0-63   from xd (HWC f16, uint4 loads)
// Phase A2: halo ch 64-127 from inter (CHW fp32, coalesced rows, cvt->f16)
// Phase B : om GEMM M=32 N=32 K=1152, waves split K(2) x N(2), 36 MFMA each.
// Phase D1/E1: gather taps 0-4, GEMM s=0..9;  D2/E2: taps 5-8, s=10..17.
// ---------------------------------------------------------------------------
__global__ __launch_bounds__(256, 6) void k_dcn(const short* __restrict__ xd,
                                                const float* __restrict__ inter,
                                                const short* __restrict__ wtbF,
                                                const short* __restrict__ wtbomF,
                                                const float* __restrict__ b_om,
                                                const float* __restrict__ bias,
                                                float* __restrict__ out) {
  __shared__ __align__(16) char smem[26112];
  short*    sH    = (short*)smem;
  float*    sPart = (float*)smem;                 // over dead sH, after barrier
  unsigned* sPar  = (unsigned*)(smem + 20480);    // outside sV window
  short*    sV    = (short*)smem;
  unsigned* sHw   = (unsigned*)smem;              // word view of sH

  const int blk = blockIdx.x;
  const int b   = blk >> 9;
  const int hw0 = (blk & 511) * 32;
  const int h0  = hw0 >> 7;
  const int x0  = hw0 & 127;
  const int tid = threadIdx.x;
  const int l15 = tid & 15, quad = (tid & 63) >> 4, wave = tid >> 6;
  const int kh = wave >> 1, nh = wave & 1;

  const short* xdb = xd + (size_t)b * HW * 64;

  // ---- phase A: halo ch 0..63 from xd (HWC f16) ----
  for (int item = tid; item < 816; item += 256) {
    int g = item & 7, prow = item >> 3;           // prow = r3*34 + c34
    int r3 = prow / 34, c34 = prow - r3 * 34;
    int y = h0 + r3 - 1;
    int x = x0 + c34 - 1;
    uint4 v = make_uint4(0, 0, 0, 0);
    if (((unsigned)y < 128u) && ((unsigned)x < 128u))
      v = *(const uint4*)(xdb + (size_t)(y * 128 + x) * 64 + g * 8);
    *(uint4*)(&sH[(g * 102 + prow) * 8]) = v;
  }
  // ---- phase A2: halo ch 64..127 from inter (CHW fp32) ----
  {
    const float* ib = inter + (size_t)b * CIN * HW;
    for (int item = tid; item < 3264; item += 256) {
      int cp = item / 102;                        // ch-pair 0..31 (ch 2cp,2cp+1)
      int prow = item - cp * 102;
      int r3 = prow / 34, c34 = prow - r3 * 34;
      int y = h0 + r3 - 1;
      int x = x0 + c34 - 1;
      unsigned val = 0;
      if (((unsigned)y < 128u) && ((unsigned)x < 128u)) {
        const float* p = ib + (size_t)(2 * cp) * HW + y * 128 + x;
        val = packh2(p[0], p[HW]);
      }
      sHw[((8 + (cp >> 2)) * 102 + prow) * 4 + (cp & 3)] = val;
    }
  }
  __syncthreads();                               // bar1: sH ready

  // ---- phase B: om GEMM, wave = (kh) x (nh), accs stay in regs ----
  floatx4 oa = {0.f,0.f,0.f,0.f}, oc = {0.f,0.f,0.f,0.f};
#pragma unroll
  for (int i = 0; i < 18; ++i) {
    int s = kh * 18 + i;                        // [0,36)
    int tap = s >> 2;
    int ty = tap / 3, tx = tap % 3;
    int g = (s * 4 + quad) & 15;
    const short* aF = wtbomF + (size_t)s * 1024 + (quad * 16 + l15) * 8;
    half8 a0 = *(const half8*)aF;
    half8 a1 = *(const half8*)(aF + 512);
    half8 bb = *(const half8*)(&sH[(g * 102 + ty * 34 + tx + nh * 16 + l15) * 8]);
    oa = __builtin_amdgcn_mfma_f32_16x16x32_f16(a0, bb, oa, 0, 0, 0);
    oc = __builtin_amdgcn_mfma_f32_16x16x32_f16(a1, bb, oc, 0, 0, 0);
  }
  __syncthreads();                               // bar2: sH dead, Part region free
  {
    float* pw = sPart + kh * 864 + nh * 16 + l15;
#pragma unroll
    for (int r = 0; r < 4; ++r) {
      int row0 = quad * 4 + r;                  // tile 0 rows: 0..15
      pw[row0 * 32] = oa[r];
      int row1 = 16 + quad * 4 + r;             // tile 1 rows: 16..31
      if (row1 < 27) pw[row1 * 32] = oc[r];
    }
  }
  __syncthreads();                               // bar3: Part ready

  // ---- phase C: bilinear params (reduce K-halves + b_om inline) ----
  for (int item = tid; item < 288; item += 256) {
    int k  = item >> 5;
    int px = item & 31;
    float dy = sPart[(2 * k) * 32 + px]     + sPart[864 + (2 * k) * 32 + px]     + b_om[2 * k];
    float dx = sPart[(2 * k + 1) * 32 + px] + sPart[864 + (2 * k + 1) * 32 + px] + b_om[2 * k + 1];
    float mr = sPart[(18 + k) * 32 + px]    + sPart[864 + (18 + k) * 32 + px]    + b_om[18 + k];
    int h = h0, w = x0 + px;
    float m  = 1.f / (1.f + __expf(-mr));
    float py  = (float)(k / 3 - 1 + h) + dy;
    float pxx = (float)(k % 3 - 1 + w) + dx;
    float y0f = floorf(py), x0f = floorf(pxx);
    float fy = py - y0f, fx = pxx - x0f;
    int y0 = (int)y0f, x0c = (int)x0f;
    int y1 = y0 + 1, x1 = x0c + 1;
    float vy0 = ((unsigned)y0 < 128u) ? 1.f : 0.f;
    float vy1 = ((unsigned)y1 < 128u) ? 1.f : 0.f;
    float hx0 = ((unsigned)x0c < 128u) ? (1.f - fx) : 0.f;
    float hx1 = ((unsigned)x1 < 128u) ? fx : 0.f;
    int yc0 = min(max(y0, 0), 127), yc1 = min(max(y1, 0), 127);
    int xc0 = min(max(x0c, 0), 127), xc1 = min(max(x1, 0), 127);
    int xb  = min(xc0, 126);
    float wA = (xc0 == xb     ? hx0 : 0.f) + (xc1 == xb     ? hx1 : 0.f);
    float wB = (xc0 == xb + 1 ? hx0 : 0.f) + (xc1 == xb + 1 ? hx1 : 0.f);
    float gy0 = (1.f - fy) * vy0 * m, gy1 = fy * vy1 * m;
    int base = (k * 32 + px) * 3;
    sPar[base + 0] = packh2(gy0 * wA, gy0 * wB);
    sPar[base + 1] = packh2(gy1 * wA, gy1 * wB);
    sPar[base + 2] = (unsigned)(yc0 * 128 + xb) | ((unsigned)(yc1 * 128 + xb) << 16);
  }
  __syncthreads();                               // bar4: Par ready, Part dead

  const int g0  = tid & 7;
  const int px1 = tid >> 3;
  const short* xtb = xdb + g0 * 8;
  const int slot = (g0 ^ (px1 & 7)) * 8;
  const int ob0 = wave * 32;
  const int afrag = (quad * 16 + l15) * 8;
  const int xkey = (l15 & 7);
  floatx4 acc00 = {0.f,0.f,0.f,0.f}, acc01 = {0.f,0.f,0.f,0.f};
  floatx4 acc10 = {0.f,0.f,0.f,0.f}, acc11 = {0.f,0.f,0.f,0.f};

#pragma unroll
  for (int half = 0; half < 2; ++half) {
    const int j0 = half ? 5 : 0;
    const int jn = half ? 4 : 5;
    const int s0 = half ? 10 : 0;
    const int sn = half ? 8 : 10;

    // ---- phase D: gather jn taps x 8ch/thread, packed-f16 bilinear ----
#pragma unroll 3
    for (int jl = 0; jl < jn; ++jl) {
      int j = j0 + jl;
      int pbase = (j * 32 + px1) * 3;
      unsigned w0 = sPar[pbase + 0];             // (gy0*wA, gy0*wB) f16x2 (LDS bcast)
      unsigned w1 = sPar[pbase + 1];             // (gy1*wA, gy1*wB) f16x2
      unsigned of = sPar[pbase + 2];
      int offA = of & 0xffff, offB = of >> 16;
      const short* pa = xtb + (size_t)offA * 64;
      const short* pb = xtb + (size_t)offB * 64;
      uint4 A  = *(const uint4*)pa;
      uint4 Bv = *(const uint4*)(pa + 64);
      uint4 C  = *(const uint4*)pb;
      uint4 D  = *(const uint4*)(pb + 64);
      unsigned res[4];
      const unsigned* Au = (const unsigned*)&A;
      const unsigned* Bu = (const unsigned*)&Bv;
      const unsigned* Cu = (const unsigned*)&C;
      const unsigned* Du = (const unsigned*)&D;
#pragma unroll
      for (int d = 0; d < 4; ++d) {
        unsigned acc = pk_mul_blo(Au[d], w0);
        acc = pk_fma_bhi(Bu[d], w0, acc);
        acc = pk_fma_blo(Cu[d], w1, acc);
        acc = pk_fma_bhi(Du[d], w1, acc);
        res[d] = acc;
      }
      *(uint4*)(&sV[(jl * 32 + px1) * 64 + slot]) =
          make_uint4(res[0], res[1], res[2], res[3]);
    }
    __syncthreads();                             // sV half ready

    // ---- phase E: main GEMM half ----
#pragma unroll 5
    for (int si = 0; si < sn; ++si) {
      int s = s0 + si;
      const short* aF = wtbF + (size_t)(s * 4 + wave) * 1024;
      half8 a0 = *(const half8*)(aF + afrag);
      half8 a1 = *(const half8*)(aF + 512 + afrag);
      int jl = (s >> 1) - j0;
      int oct = ((s & 1) * 4 + quad) ^ xkey;    // swizzled octet slot
      half8 bb0 = *(const half8*)(&sV[(jl * 32 + l15) * 64 + oct * 8]);
      half8 bb1 = *(const half8*)(&sV[(jl * 32 + 16 + l15) * 64 + oct * 8]);
      acc00 = __builtin_amdgcn_mfma_f32_16x16x32_f16(a0, bb0, acc00, 0, 0, 0);
      acc01 = __builtin_amdgcn_mfma_f32_16x16x32_f16(a0, bb1, acc01, 0, 0, 0);
      acc10 = __builtin_amdgcn_mfma_f32_16x16x32_f16(a1, bb0, acc10, 0, 0, 0);
      acc11 = __builtin_amdgcn_mfma_f32_16x16x32_f16(a1, bb1, acc11, 0, 0, 0);
    }
    if (half == 0) __syncthreads();              // E1 done reading before D2 writes
  }

  // ---- epilogue ----
  float* outb = out + (size_t)b * COUT * HW + hw0;
#pragma unroll
  for (int r = 0; r < 4; ++r) {
    int o = ob0 + quad * 4 + r;
    float bo = bias[o];
    outb[(size_t)o * HW + l15]      = acc00[r] + bo;
    outb[(size_t)o * HW + 16 + l15] = acc01[r] + bo;
    int o1 = o + 16;
    float bo1 = bias[o1];
    outb[(size_t)o1 * HW + l15]      = acc10[r] + bo1;
    outb[(size_t)o1 * HW + 16 + l15] = acc11[r] + bo1;
  }
}

// ---------------------------------------------------------------------------
extern "C" void kernel_launch(void* const* d_in, const int* in_sizes, int n_in,
                              void* d_out, int out_size, void* d_ws, size_t ws_size,
                              hipStream_t stream) {
  const float* input_feat = (const float*)d_in[0];  // [4,64,128,128]
  const float* inter      = (const float*)d_in[1];  // [4,64,128,128]
  const float* weight     = (const float*)d_in[2];  // [128,64,3,3]
  const float* bias       = (const float*)d_in[3];  // [128]
  const float* w_om       = (const float*)d_in[4];  // [27,128,3,3]
  const float* b_om       = (const float*)d_in[5];  // [27]
  float* out = (float*)d_out;                       // [4,128,128,128]

  short* wtbF   = (short*)d_ws;                          // 147456 B
  short* wtbomF = (short*)((char*)d_ws + 147456);        // 73728 B
  short* xd     = (short*)((char*)d_ws + 221184);        // 8388608 B

  k_tr<<<NB * (HW / 64), 256, 0, stream>>>(input_feat, weight, w_om,
                                           xd, wtbF, wtbomF);
  k_dcn<<<NB * (HW / 32), 256, 0, stream>>>(xd, inter, wtbF, wtbomF, b_om, bias, out);
}

// Round 4
// 125.476 us; speedup vs baseline: 1.0920x; 1.0920x over previous
//
#include <hip/hip_runtime.h>
#include <hip/hip_fp16.h>

// B=4, Cin=64, Cout=128, H=W=128, 3x3, stride=1, pad=1, dil=1
#define HW    16384
#define NB    4
#define CIN   64
#define COUT  128

typedef short  short8  __attribute__((ext_vector_type(8)));
typedef _Float16 half8 __attribute__((ext_vector_type(8)));
typedef float  floatx4 __attribute__((ext_vector_type(4)));

__device__ __forceinline__ unsigned packh2(float a, float b) {
  __half2 h = __floats2half2_rn(a, b);
  return *(unsigned*)&h;
}
__device__ __forceinline__ short f2h(float f) {
  __half h = __float2half(f);
  return *(short*)&h;
}

// ---- packed-f16 bilinear helpers: broadcast one half of w via op_sel ----
__device__ __forceinline__ unsigned pk_mul_blo(unsigned a, unsigned w) {
  unsigned d;
  asm("v_pk_mul_f16 %0, %1, %2 op_sel:[0,0] op_sel_hi:[1,0]"
      : "=v"(d) : "v"(a), "v"(w));
  return d;
}
__device__ __forceinline__ unsigned pk_fma_blo(unsigned a, unsigned w, unsigned c) {
  unsigned d;
  asm("v_pk_fma_f16 %0, %1, %2, %3 op_sel:[0,0,0] op_sel_hi:[1,0,1]"
      : "=v"(d) : "v"(a), "v"(w), "v"(c));
  return d;
}
__device__ __forceinline__ unsigned pk_fma_bhi(unsigned a, unsigned w, unsigned c) {
  unsigned d;
  asm("v_pk_fma_f16 %0, %1, %2, %3 op_sel:[0,1,0] op_sel_hi:[1,1,1]"
      : "=v"(d) : "v"(a), "v"(w), "v"(c));
  return d;
}

// ---------------------------------------------------------------------------
// k_tr: CHW fp32 -> HWC f16 (xd=input_feat, xi=inter) + fused weight prep.
//  wtbF   [s18][wave4][tile2][quad4][l16][8] ; k=s*32+q*8+i, c=k&63,  tap=k>>6
//  wtbomF [s36][tile2][quad4][l16][8]        ; k=s*32+q*8+i, c=k&127, tap=k>>7
// ---------------------------------------------------------------------------
__global__ __launch_bounds__(256) void k_tr(const float* __restrict__ x,
                                            const float* __restrict__ inter,
                                            const float* __restrict__ weight,
                                            const float* __restrict__ w_om,
                                            short* __restrict__ xd,
                                            short* __restrict__ xi,
                                            short* __restrict__ wtbF,
                                            short* __restrict__ wtbomF) {
  __shared__ unsigned sT[64][69];
  const int blk = blockIdx.x;
  const int b = blk >> 8, hw0 = (blk & 255) * 64;
  const int tid = threadIdx.x;
  const int px = tid & 63, cg = tid >> 6;
  const float* s0 = x     + (size_t)b * CIN * HW + hw0 + px;
  const float* s1 = inter + (size_t)b * CIN * HW + hw0 + px;
#pragma unroll
  for (int step = 0; step < 16; ++step) {
    int cp = step * 4 + cg;
    int c = cp * 2;
    const float* s = (c < 64) ? (s0 + c * HW) : (s1 + (c - 64) * HW);
    sT[px][cp] = packh2(s[0], s[HW]);
  }
  // fused weight prep while LDS settles
  {
    int i = blk * 256 + tid;
    if (i < 73728) {
      int i8 = i & 7, l = (i >> 3) & 15, q = (i >> 7) & 3;
      int t = (i >> 9) & 1, wv = (i >> 10) & 3, s = i >> 12;
      int o = wv * 32 + t * 16 + l;
      int k = s * 32 + q * 8 + i8;
      int c = k & 63, tap = k >> 6;
      wtbF[i] = f2h(weight[o * 576 + c * 9 + tap]);
    }
    if (i < 36864) {
      int i8 = i & 7, l = (i >> 3) & 15, q = (i >> 7) & 3;
      int t = (i >> 9) & 1, s = i >> 10;
      int o = t * 16 + l;
      int k = s * 32 + q * 8 + i8;
      int c = k & 127, tap = k >> 7;
      wtbomF[i] = (o < 27) ? f2h(w_om[o * 1152 + c * 9 + tap]) : (short)0;
    }
  }
  __syncthreads();
  const int od = tid & 7, p0 = tid >> 3;
#pragma unroll
  for (int it = 0; it < 2; ++it) {
    int p = p0 + it * 32;
    uint4 a, bvec;
    a.x = sT[p][od * 4 + 0]; a.y = sT[p][od * 4 + 1];
    a.z = sT[p][od * 4 + 2]; a.w = sT[p][od * 4 + 3];
    bvec.x = sT[p][32 + od * 4 + 0]; bvec.y = sT[p][32 + od * 4 + 1];
    bvec.z = sT[p][32 + od * 4 + 2]; bvec.w = sT[p][32 + od * 4 + 3];
    size_t base = ((size_t)b * HW + hw0 + p) * 64 + od * 8;
    *(uint4*)(xd + base) = a;
    *(uint4*)(xi + base) = bvec;
  }
}

// ---------------------------------------------------------------------------
// k_dcn: FUSED offset/mask conv + modulated deformable conv. 64-px tile,
// 512 threads (8 waves), 1024 blocks, XCD-swizzled blockIdx.
// LDS = 50688 B -> 3 blocks/CU (24 waves/CU):
//  sH    @0      halo 3x66x128ch f16             50688 B (live A->B)
//  sPart @0      om partials [kh2][32r][64c] f32 16384 B (live postB->C)
//  sPar  @40960  packed bilinear params           6912 B (live C->D2, above sV)
//  sV    @0      V panel [tapLoc*64+px][64] XOR  <=40960 B (5-tap / 4-tap halves)
// Phase B: om GEMM M=32 N=64 K=1152, waves = K(2) x N(4), 36 MFMA each.
// Phase E: main GEMM M=128 N=64 K=576, waves = M(4) x N(2), 18 steps.
// Phase D1/E1: gather taps 0-4, GEMM s=0..9;  D2/E2: taps 5-8, s=10..17.
// ---------------------------------------------------------------------------
__global__ __launch_bounds__(512, 6) void k_dcn(const short* __restrict__ xd,
                                                const short* __restrict__ xi,
                                                const short* __restrict__ wtbF,
                                                const short* __restrict__ wtbomF,
                                                const float* __restrict__ b_om,
                                                const float* __restrict__ bias,
                                                float* __restrict__ out) {
  __shared__ __align__(16) char smem[50688];
  short*    sH    = (short*)smem;
  float*    sPart = (float*)smem;                 // over dead sH, after bar2
  unsigned* sPar  = (unsigned*)(smem + 40960);    // above sV window
  short*    sV    = (short*)smem;

  // XCD-aware swizzle: 1024 blocks -> 128-block contiguous chunk per XCD
  const int blk = (int)(blockIdx.x & 7) * 128 + (int)(blockIdx.x >> 3);
  const int b    = blk >> 8;
  const int tile = blk & 255;                     // 2 tiles per image row
  const int h0   = tile >> 1;
  const int x0   = (tile & 1) << 6;
  const int hw0  = h0 * 128 + x0;
  const int tid  = threadIdx.x;
  const int l15 = tid & 15, quad = (tid & 63) >> 4, wave = tid >> 6;

  const short* xdb = xd + (size_t)b * HW * 64;
  const short* xib = xi + (size_t)b * HW * 64;

  // ---- phase A: halo patch 3 rows x 66 cols x 128 ch ----
  for (int item = tid; item < 3168; item += 512) {
    int g = item & 15, prow = item >> 4;        // prow = r3*66 + c66
    int r3 = prow / 66, c66 = prow - r3 * 66;
    int y = h0 + r3 - 1;
    int x = x0 + c66 - 1;
    uint4 v = make_uint4(0, 0, 0, 0);
    if (((unsigned)y < 128u) && ((unsigned)x < 128u)) {
      const short* src = (g < 8)
          ? (xdb + (size_t)(y * 128 + x) * 64 + g * 8)
          : (xib + (size_t)(y * 128 + x) * 64 + (g - 8) * 8);
      v = *(const uint4*)src;
    }
    *(uint4*)(&sH[(g * 198 + prow) * 8]) = v;
  }
  __syncthreads();                               // bar1: sH ready

  // ---- phase B: om GEMM, wave = (kh = wave>>2) x (wn = wave&3) ----
  {
    const int kh = wave >> 2, wn = wave & 3;
    floatx4 oa = {0.f,0.f,0.f,0.f}, oc = {0.f,0.f,0.f,0.f};
#pragma unroll
    for (int i = 0; i < 18; ++i) {
      int s = kh * 18 + i;                      // [0,36)
      int tap = s >> 2;
      int ty = tap / 3, tx = tap % 3;
      int g = (s * 4 + quad) & 15;
      const short* aF = wtbomF + (size_t)s * 1024 + (quad * 16 + l15) * 8;
      half8 a0 = *(const half8*)aF;
      half8 a1 = *(const half8*)(aF + 512);
      half8 bb = *(const half8*)(&sH[(g * 198 + ty * 66 + tx + wn * 16 + l15) * 8]);
      oa = __builtin_amdgcn_mfma_f32_16x16x32_f16(a0, bb, oa, 0, 0, 0);
      oc = __builtin_amdgcn_mfma_f32_16x16x32_f16(a1, bb, oc, 0, 0, 0);
    }
    __syncthreads();                             // bar2: sH dead, Part free
    float* pw = sPart + kh * 2048 + wn * 16 + l15;
#pragma unroll
    for (int r = 0; r < 4; ++r) {
      int row0 = quad * 4 + r;                  // tile 0 rows: 0..15
      pw[row0 * 64] = oa[r];
      int row1 = 16 + quad * 4 + r;             // tile 1 rows: 16..31
      if (row1 < 27) pw[row1 * 64] = oc[r];
    }
  }
  __syncthreads();                               // bar3: Part ready

  // ---- phase C: bilinear params (reduce K-halves + b_om inline) ----
  for (int item = tid; item < 576; item += 512) {
    int k  = item >> 6;
    int px = item & 63;
    float dy = sPart[(2 * k) * 64 + px]     + sPart[2048 + (2 * k) * 64 + px]     + b_om[2 * k];
    float dx = sPart[(2 * k + 1) * 64 + px] + sPart[2048 + (2 * k + 1) * 64 + px] + b_om[2 * k + 1];
    float mr = sPart[(18 + k) * 64 + px]    + sPart[2048 + (18 + k) * 64 + px]    + b_om[18 + k];
    int h = h0, w = x0 + px;
    float m  = 1.f / (1.f + __expf(-mr));
    float py  = (float)(k / 3 - 1 + h) + dy;
    float pxx = (float)(k % 3 - 1 + w) + dx;
    float y0f = floorf(py), x0f = floorf(pxx);
    float fy = py - y0f, fx = pxx - x0f;
    int y0 = (int)y0f, x0c = (int)x0f;
    int y1 = y0 + 1, x1 = x0c + 1;
    float vy0 = ((unsigned)y0 < 128u) ? 1.f : 0.f;
    float vy1 = ((unsigned)y1 < 128u) ? 1.f : 0.f;
    float hx0 = ((unsigned)x0c < 128u) ? (1.f - fx) : 0.f;
    float hx1 = ((unsigned)x1 < 128u) ? fx : 0.f;
    int yc0 = min(max(y0, 0), 127), yc1 = min(max(y1, 0), 127);
    int xc0 = min(max(x0c, 0), 127), xc1 = min(max(x1, 0), 127);
    int xb  = min(xc0, 126);
    float wA = (xc0 == xb     ? hx0 : 0.f) + (xc1 == xb     ? hx1 : 0.f);
    float wB = (xc0 == xb + 1 ? hx0 : 0.f) + (xc1 == xb + 1 ? hx1 : 0.f);
    float gy0 = (1.f - fy) * vy0 * m, gy1 = fy * vy1 * m;
    int base = (k * 64 + px) * 3;
    sPar[base + 0] = packh2(gy0 * wA, gy0 * wB);
    sPar[base + 1] = packh2(gy1 * wA, gy1 * wB);
    sPar[base + 2] = (unsigned)(yc0 * 128 + xb) | ((unsigned)(yc1 * 128 + xb) << 16);
  }
  __syncthreads();                               // bar4: Par ready, Part dead

  const int g0  = tid & 7;
  const int px1 = tid >> 3;                      // 0..63
  const short* xtb = xdb + g0 * 8;
  const int slot = (g0 ^ (px1 & 7)) * 8;
  const int wm = wave >> 1, wn2 = wave & 1;      // E: M(4) x N(2)
  const int afrag = (quad * 16 + l15) * 8;
  const int xkey = (l15 & 7);
  floatx4 acc00 = {0.f,0.f,0.f,0.f}, acc01 = {0.f,0.f,0.f,0.f};
  floatx4 acc10 = {0.f,0.f,0.f,0.f}, acc11 = {0.f,0.f,0.f,0.f};

#pragma unroll
  for (int half = 0; half < 2; ++half) {
    const int j0 = half ? 5 : 0;
    const int jn = half ? 4 : 5;
    const int s0 = half ? 10 : 0;
    const int sn = half ? 8 : 10;

    // ---- phase D: gather jn taps x 8ch/thread, packed-f16 bilinear ----
#pragma unroll 3
    for (int jl = 0; jl < jn; ++jl) {
      int j = j0 + jl;
      int pbase = (j * 64 + px1) * 3;
      unsigned w0 = sPar[pbase + 0];             // (gy0*wA, gy0*wB) f16x2
      unsigned w1 = sPar[pbase + 1];             // (gy1*wA, gy1*wB) f16x2
      unsigned of = sPar[pbase + 2];
      int offA = of & 0xffff, offB = of >> 16;
      const short* pa = xtb + (size_t)offA * 64;
      const short* pb = xtb + (size_t)offB * 64;
      uint4 A  = *(const uint4*)pa;
      uint4 Bv = *(const uint4*)(pa + 64);
      uint4 C  = *(const uint4*)pb;
      uint4 D  = *(const uint4*)(pb + 64);
      unsigned res[4];
      const unsigned* Au = (const unsigned*)&A;
      const unsigned* Bu = (const unsigned*)&Bv;
      const unsigned* Cu = (const unsigned*)&C;
      const unsigned* Du = (const unsigned*)&D;
#pragma unroll
      for (int d = 0; d < 4; ++d) {
        unsigned acc = pk_mul_blo(Au[d], w0);
        acc = pk_fma_bhi(Bu[d], w0, acc);
        acc = pk_fma_blo(Cu[d], w1, acc);
        acc = pk_fma_bhi(Du[d], w1, acc);
        res[d] = acc;
      }
      *(uint4*)(&sV[(jl * 64 + px1) * 64 + slot]) =
          make_uint4(res[0], res[1], res[2], res[3]);
    }
    __syncthreads();                             // sV half ready

    // ---- phase E: main GEMM half ----
#pragma unroll 5
    for (int si = 0; si < sn; ++si) {
      int s = s0 + si;
      const short* aF = wtbF + (size_t)(s * 4 + wm) * 1024;
      half8 a0 = *(const half8*)(aF + afrag);
      half8 a1 = *(const half8*)(aF + 512 + afrag);
      int jl = (s >> 1) - j0;
      int oct = ((s & 1) * 4 + quad) ^ xkey;    // swizzled octet slot
      half8 bb0 = *(const half8*)(&sV[(jl * 64 + wn2 * 32 + l15) * 64 + oct * 8]);
      half8 bb1 = *(const half8*)(&sV[(jl * 64 + wn2 * 32 + 16 + l15) * 64 + oct * 8]);
      acc00 = __builtin_amdgcn_mfma_f32_16x16x32_f16(a0, bb0, acc00, 0, 0, 0);
      acc01 = __builtin_amdgcn_mfma_f32_16x16x32_f16(a0, bb1, acc01, 0, 0, 0);
      acc10 = __builtin_amdgcn_mfma_f32_16x16x32_f16(a1, bb0, acc10, 0, 0, 0);
      acc11 = __builtin_amdgcn_mfma_f32_16x16x32_f16(a1, bb1, acc11, 0, 0, 0);
    }
    if (half == 0) __syncthreads();              // E1 done reading before D2 writes
  }

  // ---- epilogue ----
  float* outb = out + (size_t)b * COUT * HW + hw0 + wn2 * 32;
#pragma unroll
  for (int r = 0; r < 4; ++r) {
    int o = wm * 32 + quad * 4 + r;
    float bo = bias[o];
    outb[(size_t)o * HW + l15]      = acc00[r] + bo;
    outb[(size_t)o * HW + 16 + l15] = acc01[r] + bo;
    int o1 = o + 16;
    float bo1 = bias[o1];
    outb[(size_t)o1 * HW + l15]      = acc10[r] + bo1;
    outb[(size_t)o1 * HW + 16 + l15] = acc11[r] + bo1;
  }
}

// ---------------------------------------------------------------------------
extern "C" void kernel_launch(void* const* d_in, const int* in_sizes, int n_in,
                              void* d_out, int out_size, void* d_ws, size_t ws_size,
                              hipStream_t stream) {
  const float* input_feat = (const float*)d_in[0];  // [4,64,128,128]
  const float* inter      = (const float*)d_in[1];  // [4,64,128,128]
  const float* weight     = (const float*)d_in[2];  // [128,64,3,3]
  const float* bias       = (const float*)d_in[3];  // [128]
  const float* w_om       = (const float*)d_in[4];  // [27,128,3,3]
  const float* b_om       = (const float*)d_in[5];  // [27]
  float* out = (float*)d_out;                       // [4,128,128,128]

  short* wtbF   = (short*)d_ws;                          // 147456 B
  short* wtbomF = (short*)((char*)d_ws + 147456);        // 73728 B
  short* xd     = (short*)((char*)d_ws + 221184);        // 8388608 B
  short* xi     = (short*)((char*)d_ws + 8609792);       // 8388608 B (~17 MB)

  k_tr<<<NB * (HW / 64), 256, 0, stream>>>(input_feat, inter, weight, w_om,
                                           xd, xi, wtbF, wtbomF);
  k_dcn<<<NB * (HW / 64), 512, 0, stream>>>(xd, xi, wtbF, wtbomF, b_om, bias, out);
}